// Round 12
// baseline (1201.720 us; speedup 1.0000x reference)
//
#include <hip/hip_runtime.h>
#include <math.h>

#define NN 50000      // nodes
#define NE 1000000    // edges
#define D 64          // hidden
#define FIN 19
#define EHD 50        // edge attr dim
#define NG 128        // graphs
#define NBLK 3
#define NB1 196       // (NN+255)/256
#define EAPW 28       // uints per packed ea row (25 data + 3 pad, 112B, 16B-aligned)

#define PI_OVER_CUT 0.6283185307179586f
#define LN2F 0.6931471805599453f

static __device__ __forceinline__ float sspf(float x) {
  return fmaxf(x, 0.0f) + log1pf(expf(-fabsf(x))) - LN2F;
}
static __device__ __forceinline__ float sigm(float x) {
  return 1.0f / (1.0f + expf(-x));
}

typedef _Float16 h2f __attribute__((ext_vector_type(2)));   // for fdot2
typedef __fp16   p2f __attribute__((ext_vector_type(2)));   // cvt_pkrtz result

// pack two f32 into one uint of 2 f16 (RTZ, single v_cvt_pkrtz)
static __device__ __forceinline__ unsigned int f16pair(float a, float b) {
  p2f r = __builtin_amdgcn_cvt_pkrtz(a, b);
  return __builtin_bit_cast(unsigned int, r);
}

// 2-wide f16 dot with f32 accumulate: v_dot2_f32_f16 (2 MACs / instruction)
#if __has_builtin(__builtin_amdgcn_fdot2)
static __device__ __forceinline__ float dot2(unsigned int a, unsigned int b, float c) {
  return __builtin_amdgcn_fdot2(__builtin_bit_cast(h2f, a),
                                __builtin_bit_cast(h2f, b), c, false);
}
#else
static __device__ __forceinline__ float dot2(unsigned int a, unsigned int b, float c) {
  h2f a2 = __builtin_bit_cast(h2f, a), b2 = __builtin_bit_cast(h2f, b);
  return c + (float)a2.x * (float)b2.x + (float)a2.y * (float)b2.y;
}
#endif

// ---- degree count ----
__global__ __launch_bounds__(256) void k_deg(const int* __restrict__ ei,
                                             int* __restrict__ degi) {
  int e = blockIdx.x * 256 + threadIdx.x;
  if (e < NE) atomicAdd(&degi[ei[NE + e]], 1);
}

// ---- parallel scan pass 1 ----
__global__ __launch_bounds__(256) void k_scan1(int* __restrict__ degi,
                                               int* __restrict__ start,
                                               float* __restrict__ dinv,
                                               int* __restrict__ bsum) {
  __shared__ int sc[256];
  int t = threadIdx.x;
  int i = blockIdx.x * 256 + t;
  int d = (i < NN) ? degi[i] : 0;
  sc[t] = d; __syncthreads();
  for (int off = 1; off < 256; off <<= 1) {
    int u = (t >= off) ? sc[t - off] : 0;
    __syncthreads();
    sc[t] += u;
    __syncthreads();
  }
  if (i < NN) {
    start[i] = sc[t] - d;
    dinv[i] = 1.0f / fmaxf((float)d, 1.0f);
    degi[i] = 0;                          // becomes cursor for k_slot2
  }
  if (t == 255) bsum[blockIdx.x] = sc[255];
}

// ---- scan pass 2 ----
__global__ __launch_bounds__(256) void k_scan2(int* __restrict__ bsum) {
  __shared__ int sc[256];
  int t = threadIdx.x;
  int v = (t < NB1) ? bsum[t] : 0;
  sc[t] = v; __syncthreads();
  for (int off = 1; off < 256; off <<= 1) {
    int u = (t >= off) ? sc[t - off] : 0;
    __syncthreads();
    sc[t] += u;
    __syncthreads();
  }
  bsum[t] = sc[t] - v;
}

// ---- scan pass 3 ----
__global__ __launch_bounds__(256) void k_scan3(int* __restrict__ start,
                                               const int* __restrict__ bsum) {
  int i = blockIdx.x * 256 + threadIdx.x;
  if (i < NN) start[i] += bsum[blockIdx.x];
  if (i == 0) start[NN] = NE;
}

// ---- CSR slot assignment + fused f16 ea pack (stream read, scatter write) ----
template<int PACK>
__global__ __launch_bounds__(256) void k_slot2(const int* __restrict__ ei,
                                               const float* __restrict__ ew,
                                               const int* __restrict__ start,
                                               int* __restrict__ cursor,
                                               int* __restrict__ es,
                                               int* __restrict__ ssrc,
                                               int* __restrict__ sdst,
                                               float* __restrict__ Cp,
                                               const float* __restrict__ ea,
                                               unsigned int* __restrict__ eap) {
  int e = blockIdx.x * 256 + threadIdx.x;
  if (e >= NE) return;
  int dst = ei[NE + e];
  int ofs = atomicAdd(&cursor[dst], 1);
  int s = start[dst] + ofs;
  es[s] = e;
  ssrc[s] = ei[e];
  sdst[s] = dst;
  Cp[s] = cosf(ew[e] * PI_OVER_CUT) * 0.5f + 0.5f;
  if (PACK) {
    const float2* er = (const float2*)(ea + (size_t)e * EHD);  // e-order stream
    unsigned int tmp[25];
    #pragma unroll
    for (int k2 = 0; k2 < 25; k2++) {
      float2 v = er[k2];
      tmp[k2] = f16pair(v.x, v.y);
    }
    uint4* op = (uint4*)(eap + (size_t)s * EAPW);              // scatter write
    #pragma unroll
    for (int i = 0; i < 6; i++)
      op[i] = make_uint4(tmp[4*i], tmp[4*i+1], tmp[4*i+2], tmp[4*i+3]);
    op[6] = make_uint4(tmp[24], 0u, 0u, 0u);
  }
}

// ---- pack MLP weights as f16 pairs: w1h [NB][32][25], w2h [NB][64][16] ----
__global__ __launch_bounds__(256) void k_wprep(const float* __restrict__ w1,
                                               const float* __restrict__ w2,
                                               unsigned int* __restrict__ w1h,
                                               unsigned int* __restrict__ w2h) {
  int i = blockIdx.x * 256 + threadIdx.x;
  if (i < NBLK * 32 * 25) {
    int b = i / (32 * 25), r = i % (32 * 25), j = r / 25, k2 = r % 25;
    const float* src = w1 + ((size_t)(b * 32 + j) * EHD + 2 * k2);
    w1h[i] = f16pair(src[0], src[1]);
  }
  int i2 = i - NBLK * 32 * 25;
  if (i2 >= 0 && i2 < NBLK * 64 * 16) {
    int b = i2 / (64 * 16), r = i2 % (64 * 16), d = r / 16, p = r % 16;
    const float* src = w2 + ((size_t)(b * 64 + d) * 32 + 2 * p);
    w2h[i2] = f16pair(src[0], src[1]);
  }
}

// ---- graph boundaries ----
__global__ void k_bounds(const int* __restrict__ batch, int* __restrict__ bounds) {
  int g = threadIdx.x;
  if (g > NG) return;
  int lo = 0, hi = NN;
  while (lo < hi) { int mid = (lo + hi) >> 1; if (batch[mid] < g) lo = mid + 1; else hi = mid; }
  bounds[g] = lo;
}

// ---- lin0 quarter-split ----
__global__ __launch_bounds__(256) void k_lin0q(const float* __restrict__ x,
                                               const float* __restrict__ w,
                                               const float* __restrict__ bias,
                                               float* __restrict__ S) {
  int n = blockIdx.x * 256 + threadIdx.x;
  int q = blockIdx.y;
  if (n >= NN) return;
  float xr[FIN];
  #pragma unroll
  for (int k = 0; k < FIN; k++) xr[k] = x[n * FIN + k];
  #pragma unroll
  for (int i = 0; i < 16; i++) {
    int d = q * 16 + i;
    float a0 = bias[d], a1 = 0.f;
    #pragma unroll
    for (int k = 0; k < FIN - 1; k += 2) {
      a0 += xr[k] * w[d * FIN + k];
      a1 += xr[k + 1] * w[d * FIN + k + 1];
    }
    a0 += xr[FIN - 1] * w[d * FIN + FIN - 1];
    float acc = a0 + a1;
    S[(size_t)n * D + d] = acc > 0.f ? acc : 0.01f * acc;
  }
}

// ---- tiled GEMV stage (initial hx only) ----
template<int ACT>
__global__ __launch_bounds__(256) void k_stage(const float* __restrict__ in,
                                               const float* __restrict__ w,
                                               const float* __restrict__ bias,
                                               float* __restrict__ out) {
  __shared__ float tile[64 * 65];
  int tid = threadIdx.x;
  long nb = (long)blockIdx.x * 64;
  const float4* src = (const float4*)(in + nb * D);
  #pragma unroll
  for (int r = 0; r < 4; r++) {
    int idx = r * 256 + tid;
    int row = idx >> 4, c4 = idx & 15;
    float4 v = src[idx];
    float* dp = &tile[row * 65 + c4 * 4];
    dp[0] = v.x; dp[1] = v.y; dp[2] = v.z; dp[3] = v.w;
  }
  __syncthreads();
  int q = __builtin_amdgcn_readfirstlane(tid >> 6);
  int lane = tid & 63;
  float acc[16];
  const float* wr = w + q * 16 * D;
  #pragma unroll
  for (int i = 0; i < 16; i++) acc[i] = bias ? bias[q * 16 + i] : 0.0f;
  for (int k = 0; k < D; k++) {
    float a = tile[lane * 65 + k];
    #pragma unroll
    for (int i = 0; i < 16; i++) acc[i] += a * wr[i * D + k];
  }
  __syncthreads();
  #pragma unroll
  for (int i = 0; i < 16; i++) {
    float v = acc[i];
    if (ACT == 1) v = sspf(v);
    tile[lane * 65 + q * 16 + i] = v;
  }
  __syncthreads();
  float4* dst = (float4*)(out + nb * D);
  #pragma unroll
  for (int r = 0; r < 4; r++) {
    int idx = r * 256 + tid;
    int row = idx >> 4, c4 = idx & 15;
    if (nb + row < NN) {
      const float* sp = &tile[row * 65 + c4 * 4];
      dst[idx] = make_float4(sp[0], sp[1], sp[2], sp[3]);
    }
  }
}

// ---- fused edge conv: dot2-f16 MLP1+MLP2 + segmented aggregate ----
// SRC=1: coalesced f16 eap (slot order) + dot2 math.
// SRC=0: fp32 ea gathered via es + scalar FMA (ws fallback).
template<int SRC>
__global__ __launch_bounds__(256) void k_econv4(const float* __restrict__ ea,
                                                const unsigned int* __restrict__ eap,
                                                const int* __restrict__ es,
                                                const float* __restrict__ w1,
                                                const unsigned int* __restrict__ w1h,
                                                const float* __restrict__ b1,
                                                const float* __restrict__ w2,
                                                const unsigned int* __restrict__ w2h,
                                                const float* __restrict__ b2,
                                                const float* __restrict__ Cp,
                                                const int* __restrict__ ssrc,
                                                const int* __restrict__ sdst,
                                                const float* __restrict__ hx,
                                                float* __restrict__ agg) {
  __shared__ float tileAll[4 * 16 * 68];
  int tid = threadIdx.x;
  int wid = tid >> 6, lane = tid & 63;
  float* tile = tileAll + wid * (16 * 68);
  int s = blockIdx.x * 256 + tid;
  if (s >= NE) return;                     // NE%64==0: whole waves exit
  int srcn = ssrc[s];
  int me = sdst[s];
  float cv = Cp[s];
  int pm = __shfl_up(me, 1);
  bool bound = (lane == 0) || (me != pm);
  unsigned long long segmask = __ballot(bound);
  // MLP1 -> t1h (16 packed f16 pairs)
  unsigned int t1h[16];
  if (SRC == 1) {
    const uint4* ep4 = (const uint4*)(eap + (size_t)s * EAPW);
    uint4 q0 = ep4[0], q1 = ep4[1], q2 = ep4[2], q3 = ep4[3], q4 = ep4[4],
          q5 = ep4[5];
    unsigned int q6 = ((const unsigned int*)(ep4 + 6))[0];
    unsigned int arrh[25] = {q0.x, q0.y, q0.z, q0.w, q1.x, q1.y, q1.z, q1.w,
                             q2.x, q2.y, q2.z, q2.w, q3.x, q3.y, q3.z, q3.w,
                             q4.x, q4.y, q4.z, q4.w, q5.x, q5.y, q5.z, q5.w,
                             q6};
    float t1[32];
    #pragma unroll
    for (int j = 0; j < 32; j++) {
      float acc = b1[j];
      #pragma unroll
      for (int k = 0; k < 25; k++) acc = dot2(arrh[k], w1h[j * 25 + k], acc);
      t1[j] = fmaxf(acc, 0.0f);
    }
    #pragma unroll
    for (int p = 0; p < 16; p++) t1h[p] = f16pair(t1[2 * p], t1[2 * p + 1]);
  } else {
    int e = es[s];
    float arr[EHD];
    const float2* er = (const float2*)(ea + (size_t)e * EHD);
    #pragma unroll
    for (int k2 = 0; k2 < EHD / 2; k2++) {
      float2 v = er[k2];
      arr[2 * k2] = v.x; arr[2 * k2 + 1] = v.y;
    }
    float t1[32];
    #pragma unroll
    for (int j = 0; j < 32; j++) {
      float a0 = b1[j], a1 = 0.f;
      #pragma unroll
      for (int k = 0; k < EHD; k += 2) {
        a0 += arr[k]     * w1[j * EHD + k];
        a1 += arr[k + 1] * w1[j * EHD + k + 1];
      }
      t1[j] = fmaxf(a0 + a1, 0.0f);
    }
    #pragma unroll
    for (int p = 0; p < 16; p++) t1h[p] = f16pair(t1[2 * p], t1[2 * p + 1]);
  }
  const float4* hrow = (const float4*)(hx + (size_t)srcn * D);
  int dim = lane >> 2, r = lane & 3;
  #pragma unroll
  for (int c = 0; c < 4; c++) {
    float4 hv[4];
    #pragma unroll
    for (int i = 0; i < 4; i++) hv[i] = hrow[c * 4 + i];
    float mg[16];
    #pragma unroll
    for (int u = 0; u < 16; u++) {
      int d = c * 16 + u;
      float acc = b2[d];
      #pragma unroll
      for (int p = 0; p < 16; p++) acc = dot2(t1h[p], w2h[d * 16 + p], acc);
      float4 h4 = hv[u >> 2];
      float hc = (u & 3) == 0 ? h4.x : (u & 3) == 1 ? h4.y
               : (u & 3) == 2 ? h4.z : h4.w;
      mg[u] = acc * cv * hc;
    }
    #pragma unroll
    for (int u = 0; u < 16; u++) tile[u * 68 + lane] = mg[u];
    asm volatile("s_waitcnt lgkmcnt(0)" ::: "memory");
    unsigned long long mask = segmask;
    while (mask) {
      int l0 = __ffsll((unsigned long long)mask) - 1;
      unsigned long long rest = mask & (mask - 1);
      int l1 = rest ? (__ffsll((unsigned long long)rest) - 1) : 64;
      mask = rest;
      int node = __shfl(me, l0);
      float v = 0.f;
      for (int sl = l0 + r; sl < l1; sl += 4)
        v += tile[dim * 68 + sl];
      v += __shfl_xor(v, 1);
      v += __shfl_xor(v, 2);
      if (r == 0)
        atomicAdd(&agg[(size_t)node * D + c * 16 + dim], v);
    }
    asm volatile("s_waitcnt lgkmcnt(0)" ::: "memory");
  }
}

// ---- fused node pipeline: (agg*dinv)->lin2+ssp->lin3->GRU->next hx ----
// 512 threads / 8 waves, each wave owns an 8-dim output slice: doubles the
// resident wave pool (grid is only ~3 WGs/CU of work -> occupancy-limited).
__global__ __launch_bounds__(512) void k_nodeblk(const float* __restrict__ agg,
                                                 const float* __restrict__ dinv,
                                                 const float* __restrict__ hin,
                                                 const float* __restrict__ w2,
                                                 const float* __restrict__ b2,
                                                 const float* __restrict__ w3,
                                                 const float* __restrict__ b3,
                                                 const float* __restrict__ wih,
                                                 const float* __restrict__ whh,
                                                 const float* __restrict__ bih,
                                                 const float* __restrict__ bhh,
                                                 float* __restrict__ hout,
                                                 const float* __restrict__ w1n,
                                                 float* __restrict__ hxout) {
  __shared__ float tA[64 * 65];
  __shared__ float tH[64 * 65];
  int tid = threadIdx.x;
  long nb = (long)blockIdx.x * 64;
  const float4* as = (const float4*)(agg + nb * D);
  const float4* hs = (const float4*)(hin + nb * D);
  #pragma unroll
  for (int r = 0; r < 2; r++) {
    int idx = r * 512 + tid;
    int row = idx >> 4, c4 = idx & 15;
    float dv = dinv[nb + row];
    float4 v = as[idx];
    float* dp = &tA[row * 65 + c4 * 4];
    dp[0] = v.x * dv; dp[1] = v.y * dv; dp[2] = v.z * dv; dp[3] = v.w * dv;
    float4 u = hs[idx];
    float* ep = &tH[row * 65 + c4 * 4];
    ep[0] = u.x; ep[1] = u.y; ep[2] = u.z; ep[3] = u.w;
  }
  __syncthreads();
  int q = __builtin_amdgcn_readfirstlane(tid >> 6);   // 0..7, wave-uniform
  int lane = tid & 63;
  // phase 1: v1 = ssp(agg @ w2^T + b2), wave computes dims q*8..q*8+7
  {
    float acc[8];
    const float* wr = w2 + q * 8 * D;
    #pragma unroll
    for (int i = 0; i < 8; i++) acc[i] = b2[q * 8 + i];
    for (int k = 0; k < D; k++) {
      float a = tA[lane * 65 + k];
      #pragma unroll
      for (int i = 0; i < 8; i++) acc[i] += a * wr[i * D + k];
    }
    __syncthreads();
    #pragma unroll
    for (int i = 0; i < 8; i++) tA[lane * 65 + q * 8 + i] = sspf(acc[i]);
    __syncthreads();
  }
  // phase 2: m = v1 @ w3^T + b3
  {
    float acc[8];
    const float* wr = w3 + q * 8 * D;
    #pragma unroll
    for (int i = 0; i < 8; i++) acc[i] = b3[q * 8 + i];
    for (int k = 0; k < D; k++) {
      float a = tA[lane * 65 + k];
      #pragma unroll
      for (int i = 0; i < 8; i++) acc[i] += a * wr[i * D + k];
    }
    __syncthreads();
    #pragma unroll
    for (int i = 0; i < 8; i++) tA[lane * 65 + q * 8 + i] = acc[i];
    __syncthreads();
  }
  // phase 3: GRU (6 gate slices of 8 dims per wave)
  {
    float ir[8], iz[8], inn[8], hr[8], hz[8], hn[8];
    #pragma unroll
    for (int i = 0; i < 8; i++) {
      int dd = q * 8 + i;
      ir[i] = bih[dd]; iz[i] = bih[D + dd]; inn[i] = bih[2 * D + dd];
      hr[i] = bhh[dd]; hz[i] = bhh[D + dd]; hn[i] = bhh[2 * D + dd];
    }
    const float* wi0 = wih + q * 8 * D;
    const float* wi1 = wih + (D + q * 8) * D;
    const float* wi2 = wih + (2 * D + q * 8) * D;
    const float* wh0 = whh + q * 8 * D;
    const float* wh1 = whh + (D + q * 8) * D;
    const float* wh2 = whh + (2 * D + q * 8) * D;
    for (int k = 0; k < D; k++) {
      float mm = tA[lane * 65 + k];
      float hh = tH[lane * 65 + k];
      #pragma unroll
      for (int i = 0; i < 8; i++) {
        ir[i]  += mm * wi0[i * D + k];
        iz[i]  += mm * wi1[i * D + k];
        inn[i] += mm * wi2[i * D + k];
        hr[i]  += hh * wh0[i * D + k];
        hz[i]  += hh * wh1[i * D + k];
        hn[i]  += hh * wh2[i * D + k];
      }
    }
    __syncthreads();
    #pragma unroll
    for (int i = 0; i < 8; i++) {
      float hold = tH[lane * 65 + q * 8 + i];
      float r = sigm(ir[i] + hr[i]);
      float zg = sigm(iz[i] + hz[i]);
      float nn2 = tanhf(inn[i] + r * hn[i]);
      tA[lane * 65 + q * 8 + i] = (1.0f - zg) * nn2 + zg * hold;
    }
    __syncthreads();
  }
  // store h'
  float4* dst = (float4*)(hout + nb * D);
  #pragma unroll
  for (int r = 0; r < 2; r++) {
    int idx = r * 512 + tid;
    int row = idx >> 4, c4 = idx & 15;
    if (nb + row < NN) {
      const float* sp = &tA[row * 65 + c4 * 4];
      dst[idx] = make_float4(sp[0], sp[1], sp[2], sp[3]);
    }
  }
  // phase 4: next-block hx = h' @ w1n^T
  if (w1n) {
    float acc[8];
    const float* wr = w1n + q * 8 * D;
    #pragma unroll
    for (int i = 0; i < 8; i++) acc[i] = 0.0f;
    for (int k = 0; k < D; k++) {
      float a = tA[lane * 65 + k];
      #pragma unroll
      for (int i = 0; i < 8; i++) acc[i] += a * wr[i * D + k];
    }
    __syncthreads();
    #pragma unroll
    for (int i = 0; i < 8; i++) tH[lane * 65 + q * 8 + i] = acc[i];
    __syncthreads();
    float4* dh = (float4*)(hxout + nb * D);
    #pragma unroll
    for (int r = 0; r < 2; r++) {
      int idx = r * 512 + tid;
      int row = idx >> 4, c4 = idx & 15;
      if (nb + row < NN) {
        const float* sp = &tH[row * 65 + c4 * 4];
        dh[idx] = make_float4(sp[0], sp[1], sp[2], sp[3]);
      }
    }
  }
}

// ---- fused Set2Set step ----
__global__ __launch_bounds__(256) void k_s2s(const float* __restrict__ wih,
                                             const float* __restrict__ whh,
                                             const float* __restrict__ bih,
                                             const float* __restrict__ bhh,
                                             const float* __restrict__ S,
                                             const int* __restrict__ bounds,
                                             float* __restrict__ qstar,
                                             float* __restrict__ hl,
                                             float* __restrict__ cl,
                                             float* __restrict__ ebuf) {
  __shared__ float qv[D];
  __shared__ float red[256];
  int g = blockIdx.x, tid = threadIdx.x;
  if (tid < D) {
    int d = tid;
    const float* qs = qstar + g * 2 * D;
    const float* hr = hl + g * D;
    float ai = bih[d]         + bhh[d];
    float af = bih[D + d]     + bhh[D + d];
    float ag = bih[2 * D + d] + bhh[2 * D + d];
    float ao = bih[3 * D + d] + bhh[3 * D + d];
    #pragma unroll 8
    for (int k = 0; k < 2 * D; k++) {
      float q = qs[k];
      ai += q * wih[d * 2 * D + k];
      af += q * wih[(D + d) * 2 * D + k];
      ag += q * wih[(2 * D + d) * 2 * D + k];
      ao += q * wih[(3 * D + d) * 2 * D + k];
    }
    #pragma unroll 8
    for (int k = 0; k < D; k++) {
      float h = hr[k];
      ai += h * whh[d * D + k];
      af += h * whh[(D + d) * D + k];
      ag += h * whh[(2 * D + d) * D + k];
      ao += h * whh[(3 * D + d) * D + k];
    }
    float c = sigm(af) * cl[g * D + d] + sigm(ai) * tanhf(ag);
    float hn = sigm(ao) * tanhf(c);
    cl[g * D + d] = c;
    hl[g * D + d] = hn;
    qstar[g * 2 * D + d] = hn;
    qv[d] = hn;
  }
  __syncthreads();
  int s = bounds[g], en = bounds[g + 1];
  float lmax = -1e30f;
  for (int n = s + tid; n < en; n += 256) {
    const float4* Sv = (const float4*)(S + (size_t)n * D);
    float a0 = 0, a1 = 0, a2 = 0, a3 = 0;
    #pragma unroll
    for (int q = 0; q < 16; q++) {
      float4 v = Sv[q];
      a0 += v.x * qv[4*q]; a1 += v.y * qv[4*q+1];
      a2 += v.z * qv[4*q+2]; a3 += v.w * qv[4*q+3];
    }
    float e = (a0 + a1) + (a2 + a3);
    ebuf[n] = e;
    lmax = fmaxf(lmax, e);
  }
  red[tid] = lmax; __syncthreads();
  for (int st = 128; st > 0; st >>= 1) {
    if (tid < st) red[tid] = fmaxf(red[tid], red[tid + st]);
    __syncthreads();
  }
  float smax = red[0]; __syncthreads();
  float lsum = 0;
  for (int n = s + tid; n < en; n += 256) {
    float p = expf(ebuf[n] - smax);
    ebuf[n] = p;
    lsum += p;
  }
  red[tid] = lsum; __syncthreads();
  for (int st = 128; st > 0; st >>= 1) {
    if (tid < st) red[tid] += red[tid + st];
    __syncthreads();
  }
  float inv = red[0] > 0.f ? 1.0f / red[0] : 0.0f;
  __syncthreads();
  int grp = tid >> 6, d = tid & 63;
  float acc = 0;
  for (int n = s + grp; n < en; n += 4)
    acc += ebuf[n] * S[(size_t)n * D + d];
  red[tid] = acc; __syncthreads();
  if (tid < D)
    qstar[g * 2 * D + D + tid] =
        (red[tid] + red[64 + tid] + red[128 + tid] + red[192 + tid]) * inv;
}

// ---- final head ----
__global__ __launch_bounds__(64) void k_final(const float* __restrict__ qstar,
                                              const float* __restrict__ w1,
                                              const float* __restrict__ b1,
                                              const float* __restrict__ w2,
                                              const float* __restrict__ b2,
                                              const int* __restrict__ z,
                                              const float* __restrict__ eref,
                                              const float* __restrict__ aref,
                                              const int* __restrict__ bounds,
                                              float* __restrict__ outp) {
  __shared__ float red[D];
  int g = blockIdx.x, d = threadIdx.x;
  const float* qs = qstar + g * 2 * D;
  float a0 = 0, a1 = 0, a2 = 0, a3 = 0;
  #pragma unroll
  for (int k = 0; k < 2 * D; k += 4) {
    a0 += qs[k]   * w1[d * 2 * D + k];
    a1 += qs[k+1] * w1[d * 2 * D + k + 1];
    a2 += qs[k+2] * w1[d * 2 * D + k + 2];
    a3 += qs[k+3] * w1[d * 2 * D + k + 3];
  }
  float gv = fmaxf((a0 + a1) + (a2 + a3) + b1[d], 0.0f);
  red[d] = gv * w2[d];
  __syncthreads();
  for (int st = 32; st > 0; st >>= 1) {
    if (d < st) red[d] += red[d + st];
    __syncthreads();
  }
  float energy = red[0] + b2[0];
  __syncthreads();
  int s = bounds[g], en = bounds[g + 1];
  float racc = 0;
  for (int n = s + d; n < en; n += 64) {
    int zz = z[n];
    racc += eref[zz] + aref[zz];
  }
  red[d] = racc; __syncthreads();
  for (int st = 32; st > 0; st >>= 1) {
    if (d < st) red[d] += red[d + st];
    __syncthreads();
  }
  if (d == 0) outp[g] = energy + red[0];
}

extern "C" void kernel_launch(void* const* d_in, const int* in_sizes, int n_in,
                              void* d_out, int out_size, void* d_ws, size_t ws_size,
                              hipStream_t stream) {
  const float* x      = (const float*)d_in[0];
  const int*   ei     = (const int*)d_in[1];
  const float* ew     = (const float*)d_in[2];
  const float* ea     = (const float*)d_in[3];
  const int*   z      = (const int*)d_in[4];
  const int*   batch  = (const int*)d_in[5];
  const float* lin0_w = (const float*)d_in[6];
  const float* lin0_b = (const float*)d_in[7];
  const float* cw1    = (const float*)d_in[8];
  const float* cb1    = (const float*)d_in[9];
  const float* cw2    = (const float*)d_in[10];
  const float* cb2    = (const float*)d_in[11];
  const float* cl1w   = (const float*)d_in[12];
  const float* cl2w   = (const float*)d_in[13];
  const float* cl2b   = (const float*)d_in[14];
  const float* cl3w   = (const float*)d_in[15];
  const float* cl3b   = (const float*)d_in[16];
  const float* gwih   = (const float*)d_in[17];
  const float* gwhh   = (const float*)d_in[18];
  const float* gbih   = (const float*)d_in[19];
  const float* gbhh   = (const float*)d_in[20];
  const float* lwih   = (const float*)d_in[21];
  const float* lwhh   = (const float*)d_in[22];
  const float* lbih   = (const float*)d_in[23];
  const float* lbhh   = (const float*)d_in[24];
  const float* l1w    = (const float*)d_in[25];
  const float* l1b    = (const float*)d_in[26];
  const float* l2w    = (const float*)d_in[27];
  const float* l2b    = (const float*)d_in[28];
  const float* aref   = (const float*)d_in[29];
  const float* eref   = (const float*)d_in[30];
  float* outp = (float*)d_out;

  const long NND = (long)NN * D;
  float* f = (float*)d_ws;
  long cur = 0;
  long oS0 = cur;   cur += NND;
  long oS1 = cur;   cur += NND;
  long oHX = cur;   cur += NND;
  long oAG = cur;   cur += NND;
  long oCP = cur;   cur += NE;
  long oDI = cur;   cur += 50176;
  long oEB = cur;   cur += 50176;  // ebuf / degi(cursor)
  long oQ  = cur;   cur += NG * 2 * D;
  long oHL = cur;   cur += NG * D;
  long oCL = cur;   cur += NG * D;
  long oBN = cur;   cur += 256;
  long oES = cur;   cur += NE;
  long oSR = cur;   cur += NE;
  long oSD = cur;   cur += NE;
  long oST = cur;   cur += 51200;
  long oBS = cur;   cur += 256;
  long oW1H = cur;  cur += 2432;   // NB*32*25 = 2400
  long oW2H = cur;  cur += 3072;   // NB*64*16
  long baseEnd = cur;

  float* S0   = f + oS0;
  float* S1   = f + oS1;
  float* hxb  = f + oHX;
  float* aggb = f + oAG;
  float* Cp   = f + oCP;
  float* dinv = f + oDI;
  float* ebuf = f + oEB;
  int*   degi = (int*)(f + oEB);
  float* qstar= f + oQ;
  float* hl   = f + oHL;
  float* cls  = f + oCL;
  int*   bounds = (int*)(f + oBN);
  int*   es   = (int*)(f + oES);
  int*   ssrc = (int*)(f + oSR);
  int*   sdst = (int*)(f + oSD);
  int*   startA = (int*)(f + oST);
  int*   bsum = (int*)(f + oBS);
  unsigned int* w1h = (unsigned int*)(f + oW1H);
  unsigned int* w2h = (unsigned int*)(f + oW2H);

  // eap: slot-ordered f16-packed ea copy, NE*EAPW uints (112 MB)
  long wsF = (long)(ws_size / 4);
  int useEap = (baseEnd + (long)NE * EAPW <= wsF) ? 1 : 0;
  unsigned int* eap = (unsigned int*)(f + baseEnd);

  hipMemsetAsync(degi, 0, NN * sizeof(int), stream);
  hipMemsetAsync(qstar, 0, (NG * 2 * D + 2 * NG * D) * sizeof(float), stream);

  k_deg<<<(NE + 255) / 256, 256, 0, stream>>>(ei, degi);
  k_scan1<<<NB1, 256, 0, stream>>>(degi, startA, dinv, bsum);
  k_scan2<<<1, 256, 0, stream>>>(bsum);
  k_scan3<<<NB1, 256, 0, stream>>>(startA, bsum);
  if (useEap) {
    k_slot2<1><<<(NE + 255) / 256, 256, 0, stream>>>(
        ei, ew, startA, degi, es, ssrc, sdst, Cp, ea, eap);
    k_wprep<<<22, 256, 0, stream>>>(cw1, cw2, w1h, w2h);
  } else {
    k_slot2<0><<<(NE + 255) / 256, 256, 0, stream>>>(
        ei, ew, startA, degi, es, ssrc, sdst, Cp, ea, eap);
  }
  k_lin0q<<<dim3((NN + 255) / 256, 4), 256, 0, stream>>>(x, lin0_w, lin0_b, S0);
  k_bounds<<<1, 192, 0, stream>>>(batch, bounds);

  const int NBK = (NN + 63) / 64;
  k_stage<0><<<NBK, 256, 0, stream>>>(S0, cl1w, nullptr, hxb);

  for (int b = 0; b < NBLK; b++) {
    float* Sin  = (b & 1) ? S1 : S0;
    float* Sout = (b & 1) ? S0 : S1;
    hipMemsetAsync(aggb, 0, NND * sizeof(float), stream);
    if (useEap)
      k_econv4<1><<<(NE + 255) / 256, 256, 0, stream>>>(
          ea, eap, es, cw1 + b * 32 * EHD, w1h + b * 800, cb1 + b * 32,
          cw2 + b * D * 32, w2h + b * 1024, cb2 + b * D,
          Cp, ssrc, sdst, hxb, aggb);
    else
      k_econv4<0><<<(NE + 255) / 256, 256, 0, stream>>>(
          ea, eap, es, cw1 + b * 32 * EHD, w1h + b * 800, cb1 + b * 32,
          cw2 + b * D * 32, w2h + b * 1024, cb2 + b * D,
          Cp, ssrc, sdst, hxb, aggb);
    const float* w1n = (b + 1 < NBLK) ? (cl1w + (b + 1) * D * D) : nullptr;
    k_nodeblk<<<NBK, 512, 0, stream>>>(aggb, dinv, Sin,
                                       cl2w + b * D * D, cl2b + b * D,
                                       cl3w + b * D * D, cl3b + b * D,
                                       gwih, gwhh, gbih, gbhh,
                                       Sout, w1n, hxb);
  }

  float* Sfin = (NBLK & 1) ? S1 : S0;
  for (int it = 0; it < 3; it++) {
    k_s2s<<<NG, 256, 0, stream>>>(lwih, lwhh, lbih, lbhh, Sfin, bounds,
                                  qstar, hl, cls, ebuf);
  }

  k_final<<<NG, 64, 0, stream>>>(qstar, l1w, l1b, l2w, l2b, z, eref, aref,
                                 bounds, outp);
}

// Round 13
// 934.043 us; speedup vs baseline: 1.2866x; 1.2866x over previous
//
#include <hip/hip_runtime.h>
#include <math.h>

#define NN 50000      // nodes
#define NE 1000000    // edges
#define D 64          // hidden
#define FIN 19
#define EHD 50        // edge attr dim
#define NG 128        // graphs
#define NBLK 3
#define NB1 196       // (NN+255)/256
#define EAPW 28       // uints per packed ea row (25 data + 3 pad, 112B, 16B-aligned)

#define PI_OVER_CUT 0.6283185307179586f
#define LN2F 0.6931471805599453f

static __device__ __forceinline__ float sspf(float x) {
  return fmaxf(x, 0.0f) + log1pf(expf(-fabsf(x))) - LN2F;
}
static __device__ __forceinline__ float sigm(float x) {
  return 1.0f / (1.0f + expf(-x));
}

typedef _Float16 h2f __attribute__((ext_vector_type(2)));   // for fdot2
typedef __fp16   p2f __attribute__((ext_vector_type(2)));   // cvt_pkrtz result

// pack two f32 into one uint of 2 f16 (RTZ, single v_cvt_pkrtz)
static __device__ __forceinline__ unsigned int f16pair(float a, float b) {
  p2f r = __builtin_amdgcn_cvt_pkrtz(a, b);
  return __builtin_bit_cast(unsigned int, r);
}
static __device__ __forceinline__ float f16lo(unsigned int u) {
  h2f v = __builtin_bit_cast(h2f, u);
  return (float)v.x;
}
static __device__ __forceinline__ float f16hi(unsigned int u) {
  h2f v = __builtin_bit_cast(h2f, u);
  return (float)v.y;
}

// 2-wide f16 dot with f32 accumulate: v_dot2_f32_f16 (2 MACs / instruction)
#if __has_builtin(__builtin_amdgcn_fdot2)
static __device__ __forceinline__ float dot2(unsigned int a, unsigned int b, float c) {
  return __builtin_amdgcn_fdot2(__builtin_bit_cast(h2f, a),
                                __builtin_bit_cast(h2f, b), c, false);
}
#else
static __device__ __forceinline__ float dot2(unsigned int a, unsigned int b, float c) {
  h2f a2 = __builtin_bit_cast(h2f, a), b2 = __builtin_bit_cast(h2f, b);
  return c + (float)a2.x * (float)b2.x + (float)a2.y * (float)b2.y;
}
#endif

// ---- degree count ----
__global__ __launch_bounds__(256) void k_deg(const int* __restrict__ ei,
                                             int* __restrict__ degi) {
  int e = blockIdx.x * 256 + threadIdx.x;
  if (e < NE) atomicAdd(&degi[ei[NE + e]], 1);
}

// ---- parallel scan pass 1 ----
__global__ __launch_bounds__(256) void k_scan1(int* __restrict__ degi,
                                               int* __restrict__ start,
                                               float* __restrict__ dinv,
                                               int* __restrict__ bsum) {
  __shared__ int sc[256];
  int t = threadIdx.x;
  int i = blockIdx.x * 256 + t;
  int d = (i < NN) ? degi[i] : 0;
  sc[t] = d; __syncthreads();
  for (int off = 1; off < 256; off <<= 1) {
    int u = (t >= off) ? sc[t - off] : 0;
    __syncthreads();
    sc[t] += u;
    __syncthreads();
  }
  if (i < NN) {
    start[i] = sc[t] - d;
    dinv[i] = 1.0f / fmaxf((float)d, 1.0f);
    degi[i] = 0;                          // becomes cursor for k_slot2
  }
  if (t == 255) bsum[blockIdx.x] = sc[255];
}

// ---- scan pass 2 ----
__global__ __launch_bounds__(256) void k_scan2(int* __restrict__ bsum) {
  __shared__ int sc[256];
  int t = threadIdx.x;
  int v = (t < NB1) ? bsum[t] : 0;
  sc[t] = v; __syncthreads();
  for (int off = 1; off < 256; off <<= 1) {
    int u = (t >= off) ? sc[t - off] : 0;
    __syncthreads();
    sc[t] += u;
    __syncthreads();
  }
  bsum[t] = sc[t] - v;
}

// ---- scan pass 3 ----
__global__ __launch_bounds__(256) void k_scan3(int* __restrict__ start,
                                               const int* __restrict__ bsum) {
  int i = blockIdx.x * 256 + threadIdx.x;
  if (i < NN) start[i] += bsum[blockIdx.x];
  if (i == 0) start[NN] = NE;
}

// ---- CSR slot assignment + fused f16 ea pack (stream read, scatter write) ----
template<int PACK>
__global__ __launch_bounds__(256) void k_slot2(const int* __restrict__ ei,
                                               const float* __restrict__ ew,
                                               const int* __restrict__ start,
                                               int* __restrict__ cursor,
                                               int* __restrict__ es,
                                               int* __restrict__ ssrc,
                                               int* __restrict__ sdst,
                                               float* __restrict__ Cp,
                                               const float* __restrict__ ea,
                                               unsigned int* __restrict__ eap) {
  int e = blockIdx.x * 256 + threadIdx.x;
  if (e >= NE) return;
  int dst = ei[NE + e];
  int ofs = atomicAdd(&cursor[dst], 1);
  int s = start[dst] + ofs;
  es[s] = e;
  ssrc[s] = ei[e];
  sdst[s] = dst;
  Cp[s] = cosf(ew[e] * PI_OVER_CUT) * 0.5f + 0.5f;
  if (PACK) {
    const float2* er = (const float2*)(ea + (size_t)e * EHD);  // e-order stream
    unsigned int tmp[25];
    #pragma unroll
    for (int k2 = 0; k2 < 25; k2++) {
      float2 v = er[k2];
      tmp[k2] = f16pair(v.x, v.y);
    }
    uint4* op = (uint4*)(eap + (size_t)s * EAPW);              // scatter write
    #pragma unroll
    for (int i = 0; i < 6; i++)
      op[i] = make_uint4(tmp[4*i], tmp[4*i+1], tmp[4*i+2], tmp[4*i+3]);
    op[6] = make_uint4(tmp[24], 0u, 0u, 0u);
  }
}

// ---- pack ALL f16 weights ----
// edge: w1h [NB][32][25], w2h [NB][64][16]
// node: nl2h/nl3h/nl1h [NB][64][32], gih/ghh [192][32]
__global__ __launch_bounds__(256) void k_wprep(const float* __restrict__ w1,
                                               const float* __restrict__ w2,
                                               const float* __restrict__ cl2w,
                                               const float* __restrict__ cl3w,
                                               const float* __restrict__ cl1w,
                                               const float* __restrict__ gwih,
                                               const float* __restrict__ gwhh,
                                               unsigned int* __restrict__ w1h,
                                               unsigned int* __restrict__ w2h,
                                               unsigned int* __restrict__ nl2h,
                                               unsigned int* __restrict__ nl3h,
                                               unsigned int* __restrict__ nl1h,
                                               unsigned int* __restrict__ gih,
                                               unsigned int* __restrict__ ghh) {
  int i = blockIdx.x * 256 + threadIdx.x;
  if (i < 2400) {                                  // w1h
    int b = i / 800, r = i % 800, j = r / 25, k2 = r % 25;
    const float* src = w1 + ((size_t)(b * 32 + j) * EHD + 2 * k2);
    w1h[i] = f16pair(src[0], src[1]);
    return;
  }
  int i2 = i - 2400;
  if (i2 < 3072) {                                 // w2h
    int b = i2 / 1024, r = i2 % 1024, d = r / 16, p = r % 16;
    const float* src = w2 + ((size_t)(b * 64 + d) * 32 + 2 * p);
    w2h[i2] = f16pair(src[0], src[1]);
    return;
  }
  int i3 = i2 - 3072;
  if (i3 < 3 * 6144) {                             // nl2h, nl3h, nl1h
    int which = i3 / 6144, j3 = i3 % 6144;
    int b = j3 / 2048, r = j3 % 2048, d = r / 32, kp = r % 32;
    const float* W = (which == 0) ? cl2w : (which == 1) ? cl3w : cl1w;
    unsigned int* O = (which == 0) ? nl2h : (which == 1) ? nl3h : nl1h;
    const float* src = W + (size_t)b * 4096 + d * 64 + 2 * kp;
    O[j3] = f16pair(src[0], src[1]);
    return;
  }
  int i4 = i3 - 3 * 6144;
  if (i4 < 2 * 6144) {                             // gih, ghh
    int which = i4 / 6144, j4 = i4 % 6144;
    int row = j4 / 32, kp = j4 % 32;
    const float* W = which ? gwhh : gwih;
    unsigned int* O = which ? ghh : gih;
    const float* src = W + (size_t)row * 64 + 2 * kp;
    O[j4] = f16pair(src[0], src[1]);
  }
}

// ---- graph boundaries ----
__global__ void k_bounds(const int* __restrict__ batch, int* __restrict__ bounds) {
  int g = threadIdx.x;
  if (g > NG) return;
  int lo = 0, hi = NN;
  while (lo < hi) { int mid = (lo + hi) >> 1; if (batch[mid] < g) lo = mid + 1; else hi = mid; }
  bounds[g] = lo;
}

// ---- lin0 quarter-split ----
__global__ __launch_bounds__(256) void k_lin0q(const float* __restrict__ x,
                                               const float* __restrict__ w,
                                               const float* __restrict__ bias,
                                               float* __restrict__ S) {
  int n = blockIdx.x * 256 + threadIdx.x;
  int q = blockIdx.y;
  if (n >= NN) return;
  float xr[FIN];
  #pragma unroll
  for (int k = 0; k < FIN; k++) xr[k] = x[n * FIN + k];
  #pragma unroll
  for (int i = 0; i < 16; i++) {
    int d = q * 16 + i;
    float a0 = bias[d], a1 = 0.f;
    #pragma unroll
    for (int k = 0; k < FIN - 1; k += 2) {
      a0 += xr[k] * w[d * FIN + k];
      a1 += xr[k + 1] * w[d * FIN + k + 1];
    }
    a0 += xr[FIN - 1] * w[d * FIN + FIN - 1];
    float acc = a0 + a1;
    S[(size_t)n * D + d] = acc > 0.f ? acc : 0.01f * acc;
  }
}

// ---- tiled GEMV stage (initial hx only) ----
template<int ACT>
__global__ __launch_bounds__(256) void k_stage(const float* __restrict__ in,
                                               const float* __restrict__ w,
                                               const float* __restrict__ bias,
                                               float* __restrict__ out) {
  __shared__ float tile[64 * 65];
  int tid = threadIdx.x;
  long nb = (long)blockIdx.x * 64;
  const float4* src = (const float4*)(in + nb * D);
  #pragma unroll
  for (int r = 0; r < 4; r++) {
    int idx = r * 256 + tid;
    int row = idx >> 4, c4 = idx & 15;
    float4 v = src[idx];
    float* dp = &tile[row * 65 + c4 * 4];
    dp[0] = v.x; dp[1] = v.y; dp[2] = v.z; dp[3] = v.w;
  }
  __syncthreads();
  int q = __builtin_amdgcn_readfirstlane(tid >> 6);
  int lane = tid & 63;
  float acc[16];
  const float* wr = w + q * 16 * D;
  #pragma unroll
  for (int i = 0; i < 16; i++) acc[i] = bias ? bias[q * 16 + i] : 0.0f;
  for (int k = 0; k < D; k++) {
    float a = tile[lane * 65 + k];
    #pragma unroll
    for (int i = 0; i < 16; i++) acc[i] += a * wr[i * D + k];
  }
  __syncthreads();
  #pragma unroll
  for (int i = 0; i < 16; i++) {
    float v = acc[i];
    if (ACT == 1) v = sspf(v);
    tile[lane * 65 + q * 16 + i] = v;
  }
  __syncthreads();
  float4* dst = (float4*)(out + nb * D);
  #pragma unroll
  for (int r = 0; r < 4; r++) {
    int idx = r * 256 + tid;
    int row = idx >> 4, c4 = idx & 15;
    if (nb + row < NN) {
      const float* sp = &tile[row * 65 + c4 * 4];
      dst[idx] = make_float4(sp[0], sp[1], sp[2], sp[3]);
    }
  }
}

// ---- fused edge conv: dot2-f16 MLP1+MLP2 + segmented aggregate ----
template<int SRC>
__global__ __launch_bounds__(256) void k_econv4(const float* __restrict__ ea,
                                                const unsigned int* __restrict__ eap,
                                                const int* __restrict__ es,
                                                const float* __restrict__ w1,
                                                const unsigned int* __restrict__ w1h,
                                                const float* __restrict__ b1,
                                                const float* __restrict__ w2,
                                                const unsigned int* __restrict__ w2h,
                                                const float* __restrict__ b2,
                                                const float* __restrict__ Cp,
                                                const int* __restrict__ ssrc,
                                                const int* __restrict__ sdst,
                                                const float* __restrict__ hx,
                                                float* __restrict__ agg) {
  __shared__ float tileAll[4 * 16 * 68];
  int tid = threadIdx.x;
  int wid = tid >> 6, lane = tid & 63;
  float* tile = tileAll + wid * (16 * 68);
  int s = blockIdx.x * 256 + tid;
  if (s >= NE) return;
  int srcn = ssrc[s];
  int me = sdst[s];
  float cv = Cp[s];
  int pm = __shfl_up(me, 1);
  bool bound = (lane == 0) || (me != pm);
  unsigned long long segmask = __ballot(bound);
  unsigned int t1h[16];
  if (SRC == 1) {
    const uint4* ep4 = (const uint4*)(eap + (size_t)s * EAPW);
    uint4 q0 = ep4[0], q1 = ep4[1], q2 = ep4[2], q3 = ep4[3], q4 = ep4[4],
          q5 = ep4[5];
    unsigned int q6 = ((const unsigned int*)(ep4 + 6))[0];
    unsigned int arrh[25] = {q0.x, q0.y, q0.z, q0.w, q1.x, q1.y, q1.z, q1.w,
                             q2.x, q2.y, q2.z, q2.w, q3.x, q3.y, q3.z, q3.w,
                             q4.x, q4.y, q4.z, q4.w, q5.x, q5.y, q5.z, q5.w,
                             q6};
    float t1[32];
    #pragma unroll
    for (int j = 0; j < 32; j++) {
      float acc = b1[j];
      #pragma unroll
      for (int k = 0; k < 25; k++) acc = dot2(arrh[k], w1h[j * 25 + k], acc);
      t1[j] = fmaxf(acc, 0.0f);
    }
    #pragma unroll
    for (int p = 0; p < 16; p++) t1h[p] = f16pair(t1[2 * p], t1[2 * p + 1]);
  } else {
    int e = es[s];
    float arr[EHD];
    const float2* er = (const float2*)(ea + (size_t)e * EHD);
    #pragma unroll
    for (int k2 = 0; k2 < EHD / 2; k2++) {
      float2 v = er[k2];
      arr[2 * k2] = v.x; arr[2 * k2 + 1] = v.y;
    }
    float t1[32];
    #pragma unroll
    for (int j = 0; j < 32; j++) {
      float a0 = b1[j], a1 = 0.f;
      #pragma unroll
      for (int k = 0; k < EHD; k += 2) {
        a0 += arr[k]     * w1[j * EHD + k];
        a1 += arr[k + 1] * w1[j * EHD + k + 1];
      }
      t1[j] = fmaxf(a0 + a1, 0.0f);
    }
    #pragma unroll
    for (int p = 0; p < 16; p++) t1h[p] = f16pair(t1[2 * p], t1[2 * p + 1]);
  }
  const float4* hrow = (const float4*)(hx + (size_t)srcn * D);
  int dim = lane >> 2, r = lane & 3;
  #pragma unroll
  for (int c = 0; c < 4; c++) {
    float4 hv[4];
    #pragma unroll
    for (int i = 0; i < 4; i++) hv[i] = hrow[c * 4 + i];
    float mg[16];
    #pragma unroll
    for (int u = 0; u < 16; u++) {
      int d = c * 16 + u;
      float acc = b2[d];
      #pragma unroll
      for (int p = 0; p < 16; p++) acc = dot2(t1h[p], w2h[d * 16 + p], acc);
      float4 h4 = hv[u >> 2];
      float hc = (u & 3) == 0 ? h4.x : (u & 3) == 1 ? h4.y
               : (u & 3) == 2 ? h4.z : h4.w;
      mg[u] = acc * cv * hc;
    }
    #pragma unroll
    for (int u = 0; u < 16; u++) tile[u * 68 + lane] = mg[u];
    asm volatile("s_waitcnt lgkmcnt(0)" ::: "memory");
    unsigned long long mask = segmask;
    while (mask) {
      int l0 = __ffsll((unsigned long long)mask) - 1;
      unsigned long long rest = mask & (mask - 1);
      int l1 = rest ? (__ffsll((unsigned long long)rest) - 1) : 64;
      mask = rest;
      int node = __shfl(me, l0);
      float v = 0.f;
      for (int sl = l0 + r; sl < l1; sl += 4)
        v += tile[dim * 68 + sl];
      v += __shfl_xor(v, 1);
      v += __shfl_xor(v, 2);
      if (r == 0)
        atomicAdd(&agg[(size_t)node * D + c * 16 + dim], v);
    }
    asm volatile("s_waitcnt lgkmcnt(0)" ::: "memory");
  }
}

// ---- fused node pipeline, f16-dot2 edition ----
// 4 waves q16 (round-11 structure); tiles stored as packed f16 pairs so every
// GEMV phase runs on v_dot2 (half the FMA instrs, half the lgkm ops).
__global__ __launch_bounds__(256) void k_nodeblk(const float* __restrict__ agg,
                                                 const float* __restrict__ dinv,
                                                 const float* __restrict__ hin,
                                                 const unsigned int* __restrict__ w2h,
                                                 const float* __restrict__ b2,
                                                 const unsigned int* __restrict__ w3h,
                                                 const float* __restrict__ b3,
                                                 const unsigned int* __restrict__ gih,
                                                 const unsigned int* __restrict__ ghh,
                                                 const float* __restrict__ bih,
                                                 const float* __restrict__ bhh,
                                                 float* __restrict__ hout,
                                                 const unsigned int* __restrict__ w1nh,
                                                 float* __restrict__ hxout) {
  __shared__ unsigned int tA[64 * 33];   // packed pairs (stride 33 -> (lane+kp)%32 banks)
  __shared__ unsigned int tH[64 * 33];
  __shared__ float tS[64 * 65];          // f32 staging for coalesced output
  int tid = threadIdx.x;
  long nb = (long)blockIdx.x * 64;
  const float4* as = (const float4*)(agg + nb * D);
  const float4* hs = (const float4*)(hin + nb * D);
  #pragma unroll
  for (int r = 0; r < 4; r++) {
    int idx = r * 256 + tid;
    int row = idx >> 4, c4 = idx & 15;
    float dv = dinv[nb + row];
    float4 v = as[idx];
    tA[row * 33 + 2 * c4]     = f16pair(v.x * dv, v.y * dv);
    tA[row * 33 + 2 * c4 + 1] = f16pair(v.z * dv, v.w * dv);
    float4 u = hs[idx];
    tH[row * 33 + 2 * c4]     = f16pair(u.x, u.y);
    tH[row * 33 + 2 * c4 + 1] = f16pair(u.z, u.w);
  }
  __syncthreads();
  int q = __builtin_amdgcn_readfirstlane(tid >> 6);
  int lane = tid & 63;
  // phase 1: v1 = ssp(agg @ w2^T + b2)
  {
    float acc[16];
    const unsigned int* wr = w2h + q * 16 * 32;
    #pragma unroll
    for (int i = 0; i < 16; i++) acc[i] = b2[q * 16 + i];
    for (int kp = 0; kp < 32; kp++) {
      unsigned int a = tA[lane * 33 + kp];
      #pragma unroll
      for (int i = 0; i < 16; i++) acc[i] = dot2(a, wr[i * 32 + kp], acc[i]);
    }
    __syncthreads();
    #pragma unroll
    for (int i = 0; i < 8; i++)
      tA[lane * 33 + q * 8 + i] = f16pair(sspf(acc[2 * i]), sspf(acc[2 * i + 1]));
    __syncthreads();
  }
  // phase 2: m = v1 @ w3^T + b3
  {
    float acc[16];
    const unsigned int* wr = w3h + q * 16 * 32;
    #pragma unroll
    for (int i = 0; i < 16; i++) acc[i] = b3[q * 16 + i];
    for (int kp = 0; kp < 32; kp++) {
      unsigned int a = tA[lane * 33 + kp];
      #pragma unroll
      for (int i = 0; i < 16; i++) acc[i] = dot2(a, wr[i * 32 + kp], acc[i]);
    }
    __syncthreads();
    #pragma unroll
    for (int i = 0; i < 8; i++)
      tA[lane * 33 + q * 8 + i] = f16pair(acc[2 * i], acc[2 * i + 1]);
    __syncthreads();
  }
  // phase 3: GRU
  {
    float ir[16], iz[16], inn[16], hr[16], hz[16], hn[16];
    #pragma unroll
    for (int i = 0; i < 16; i++) {
      int dd = q * 16 + i;
      ir[i] = bih[dd]; iz[i] = bih[D + dd]; inn[i] = bih[2 * D + dd];
      hr[i] = bhh[dd]; hz[i] = bhh[D + dd]; hn[i] = bhh[2 * D + dd];
    }
    const unsigned int* wi0 = gih + (q * 16) * 32;
    const unsigned int* wi1 = gih + (64 + q * 16) * 32;
    const unsigned int* wi2 = gih + (128 + q * 16) * 32;
    const unsigned int* wh0 = ghh + (q * 16) * 32;
    const unsigned int* wh1 = ghh + (64 + q * 16) * 32;
    const unsigned int* wh2 = ghh + (128 + q * 16) * 32;
    for (int kp = 0; kp < 32; kp++) {
      unsigned int mm = tA[lane * 33 + kp];
      unsigned int hh = tH[lane * 33 + kp];
      #pragma unroll
      for (int i = 0; i < 16; i++) {
        ir[i]  = dot2(mm, wi0[i * 32 + kp], ir[i]);
        iz[i]  = dot2(mm, wi1[i * 32 + kp], iz[i]);
        inn[i] = dot2(mm, wi2[i * 32 + kp], inn[i]);
        hr[i]  = dot2(hh, wh0[i * 32 + kp], hr[i]);
        hz[i]  = dot2(hh, wh1[i * 32 + kp], hz[i]);
        hn[i]  = dot2(hh, wh2[i * 32 + kp], hn[i]);
      }
    }
    __syncthreads();
    float hv_[16];
    #pragma unroll
    for (int i = 0; i < 16; i++) {
      unsigned int hw = tH[lane * 33 + q * 8 + (i >> 1)];
      float hold = (i & 1) ? f16hi(hw) : f16lo(hw);
      float r_ = sigm(ir[i] + hr[i]);
      float zg = sigm(iz[i] + hz[i]);
      float nn2 = tanhf(inn[i] + r_ * hn[i]);
      hv_[i] = (1.0f - zg) * nn2 + zg * hold;
      tS[lane * 65 + q * 16 + i] = hv_[i];
    }
    #pragma unroll
    for (int i = 0; i < 8; i++)
      tA[lane * 33 + q * 8 + i] = f16pair(hv_[2 * i], hv_[2 * i + 1]);
    __syncthreads();
  }
  // store h' (coalesced f32 from tS)
  float4* dst = (float4*)(hout + nb * D);
  #pragma unroll
  for (int r = 0; r < 4; r++) {
    int idx = r * 256 + tid;
    int row = idx >> 4, c4 = idx & 15;
    if (nb + row < NN) {
      const float* sp = &tS[row * 65 + c4 * 4];
      dst[idx] = make_float4(sp[0], sp[1], sp[2], sp[3]);
    }
  }
  // phase 4: next-block hx = h' @ w1n^T
  if (w1nh) {
    __syncthreads();   // all tS readers done
    float acc[16];
    const unsigned int* wr = w1nh + q * 16 * 32;
    #pragma unroll
    for (int i = 0; i < 16; i++) acc[i] = 0.0f;
    for (int kp = 0; kp < 32; kp++) {
      unsigned int a = tA[lane * 33 + kp];
      #pragma unroll
      for (int i = 0; i < 16; i++) acc[i] = dot2(a, wr[i * 32 + kp], acc[i]);
    }
    #pragma unroll
    for (int i = 0; i < 16; i++) tS[lane * 65 + q * 16 + i] = acc[i];
    __syncthreads();
    float4* dh = (float4*)(hxout + nb * D);
    #pragma unroll
    for (int r = 0; r < 4; r++) {
      int idx = r * 256 + tid;
      int row = idx >> 4, c4 = idx & 15;
      if (nb + row < NN) {
        const float* sp = &tS[row * 65 + c4 * 4];
        dh[idx] = make_float4(sp[0], sp[1], sp[2], sp[3]);
      }
    }
  }
}

// ---- fused Set2Set step ----
__global__ __launch_bounds__(256) void k_s2s(const float* __restrict__ wih,
                                             const float* __restrict__ whh,
                                             const float* __restrict__ bih,
                                             const float* __restrict__ bhh,
                                             const float* __restrict__ S,
                                             const int* __restrict__ bounds,
                                             float* __restrict__ qstar,
                                             float* __restrict__ hl,
                                             float* __restrict__ cl,
                                             float* __restrict__ ebuf) {
  __shared__ float qv[D];
  __shared__ float red[256];
  int g = blockIdx.x, tid = threadIdx.x;
  if (tid < D) {
    int d = tid;
    const float* qs = qstar + g * 2 * D;
    const float* hr = hl + g * D;
    float ai = bih[d]         + bhh[d];
    float af = bih[D + d]     + bhh[D + d];
    float ag = bih[2 * D + d] + bhh[2 * D + d];
    float ao = bih[3 * D + d] + bhh[3 * D + d];
    #pragma unroll 8
    for (int k = 0; k < 2 * D; k++) {
      float q = qs[k];
      ai += q * wih[d * 2 * D + k];
      af += q * wih[(D + d) * 2 * D + k];
      ag += q * wih[(2 * D + d) * 2 * D + k];
      ao += q * wih[(3 * D + d) * 2 * D + k];
    }
    #pragma unroll 8
    for (int k = 0; k < D; k++) {
      float h = hr[k];
      ai += h * whh[d * D + k];
      af += h * whh[(D + d) * D + k];
      ag += h * whh[(2 * D + d) * D + k];
      ao += h * whh[(3 * D + d) * D + k];
    }
    float c = sigm(af) * cl[g * D + d] + sigm(ai) * tanhf(ag);
    float hn = sigm(ao) * tanhf(c);
    cl[g * D + d] = c;
    hl[g * D + d] = hn;
    qstar[g * 2 * D + d] = hn;
    qv[d] = hn;
  }
  __syncthreads();
  int s = bounds[g], en = bounds[g + 1];
  float lmax = -1e30f;
  for (int n = s + tid; n < en; n += 256) {
    const float4* Sv = (const float4*)(S + (size_t)n * D);
    float a0 = 0, a1 = 0, a2 = 0, a3 = 0;
    #pragma unroll
    for (int q = 0; q < 16; q++) {
      float4 v = Sv[q];
      a0 += v.x * qv[4*q]; a1 += v.y * qv[4*q+1];
      a2 += v.z * qv[4*q+2]; a3 += v.w * qv[4*q+3];
    }
    float e = (a0 + a1) + (a2 + a3);
    ebuf[n] = e;
    lmax = fmaxf(lmax, e);
  }
  red[tid] = lmax; __syncthreads();
  for (int st = 128; st > 0; st >>= 1) {
    if (tid < st) red[tid] = fmaxf(red[tid], red[tid + st]);
    __syncthreads();
  }
  float smax = red[0]; __syncthreads();
  float lsum = 0;
  for (int n = s + tid; n < en; n += 256) {
    float p = expf(ebuf[n] - smax);
    ebuf[n] = p;
    lsum += p;
  }
  red[tid] = lsum; __syncthreads();
  for (int st = 128; st > 0; st >>= 1) {
    if (tid < st) red[tid] += red[tid + st];
    __syncthreads();
  }
  float inv = red[0] > 0.f ? 1.0f / red[0] : 0.0f;
  __syncthreads();
  int grp = tid >> 6, d = tid & 63;
  float acc = 0;
  for (int n = s + grp; n < en; n += 4)
    acc += ebuf[n] * S[(size_t)n * D + d];
  red[tid] = acc; __syncthreads();
  if (tid < D)
    qstar[g * 2 * D + D + tid] =
        (red[tid] + red[64 + tid] + red[128 + tid] + red[192 + tid]) * inv;
}

// ---- final head ----
__global__ __launch_bounds__(64) void k_final(const float* __restrict__ qstar,
                                              const float* __restrict__ w1,
                                              const float* __restrict__ b1,
                                              const float* __restrict__ w2,
                                              const float* __restrict__ b2,
                                              const int* __restrict__ z,
                                              const float* __restrict__ eref,
                                              const float* __restrict__ aref,
                                              const int* __restrict__ bounds,
                                              float* __restrict__ outp) {
  __shared__ float red[D];
  int g = blockIdx.x, d = threadIdx.x;
  const float* qs = qstar + g * 2 * D;
  float a0 = 0, a1 = 0, a2 = 0, a3 = 0;
  #pragma unroll
  for (int k = 0; k < 2 * D; k += 4) {
    a0 += qs[k]   * w1[d * 2 * D + k];
    a1 += qs[k+1] * w1[d * 2 * D + k + 1];
    a2 += qs[k+2] * w1[d * 2 * D + k + 2];
    a3 += qs[k+3] * w1[d * 2 * D + k + 3];
  }
  float gv = fmaxf((a0 + a1) + (a2 + a3) + b1[d], 0.0f);
  red[d] = gv * w2[d];
  __syncthreads();
  for (int st = 32; st > 0; st >>= 1) {
    if (d < st) red[d] += red[d + st];
    __syncthreads();
  }
  float energy = red[0] + b2[0];
  __syncthreads();
  int s = bounds[g], en = bounds[g + 1];
  float racc = 0;
  for (int n = s + d; n < en; n += 64) {
    int zz = z[n];
    racc += eref[zz] + aref[zz];
  }
  red[d] = racc; __syncthreads();
  for (int st = 32; st > 0; st >>= 1) {
    if (d < st) red[d] += red[d + st];
    __syncthreads();
  }
  if (d == 0) outp[g] = energy + red[0];
}

extern "C" void kernel_launch(void* const* d_in, const int* in_sizes, int n_in,
                              void* d_out, int out_size, void* d_ws, size_t ws_size,
                              hipStream_t stream) {
  const float* x      = (const float*)d_in[0];
  const int*   ei     = (const int*)d_in[1];
  const float* ew     = (const float*)d_in[2];
  const float* ea     = (const float*)d_in[3];
  const int*   z      = (const int*)d_in[4];
  const int*   batch  = (const int*)d_in[5];
  const float* lin0_w = (const float*)d_in[6];
  const float* lin0_b = (const float*)d_in[7];
  const float* cw1    = (const float*)d_in[8];
  const float* cb1    = (const float*)d_in[9];
  const float* cw2    = (const float*)d_in[10];
  const float* cb2    = (const float*)d_in[11];
  const float* cl1w   = (const float*)d_in[12];
  const float* cl2w   = (const float*)d_in[13];
  const float* cl2b   = (const float*)d_in[14];
  const float* cl3w   = (const float*)d_in[15];
  const float* cl3b   = (const float*)d_in[16];
  const float* gwih   = (const float*)d_in[17];
  const float* gwhh   = (const float*)d_in[18];
  const float* gbih   = (const float*)d_in[19];
  const float* gbhh   = (const float*)d_in[20];
  const float* lwih   = (const float*)d_in[21];
  const float* lwhh   = (const float*)d_in[22];
  const float* lbih   = (const float*)d_in[23];
  const float* lbhh   = (const float*)d_in[24];
  const float* l1w    = (const float*)d_in[25];
  const float* l1b    = (const float*)d_in[26];
  const float* l2w    = (const float*)d_in[27];
  const float* l2b    = (const float*)d_in[28];
  const float* aref   = (const float*)d_in[29];
  const float* eref   = (const float*)d_in[30];
  float* outp = (float*)d_out;

  const long NND = (long)NN * D;
  float* f = (float*)d_ws;
  long cur = 0;
  long oS0 = cur;   cur += NND;
  long oS1 = cur;   cur += NND;
  long oHX = cur;   cur += NND;
  long oAG = cur;   cur += NND;
  long oCP = cur;   cur += NE;
  long oDI = cur;   cur += 50176;
  long oEB = cur;   cur += 50176;  // ebuf / degi(cursor)
  long oQ  = cur;   cur += NG * 2 * D;
  long oHL = cur;   cur += NG * D;
  long oCL = cur;   cur += NG * D;
  long oBN = cur;   cur += 256;
  long oES = cur;   cur += NE;
  long oSR = cur;   cur += NE;
  long oSD = cur;   cur += NE;
  long oST = cur;   cur += 51200;
  long oBS = cur;   cur += 256;
  long oW1H = cur;  cur += 2432;   // NB*32*25 = 2400
  long oW2H = cur;  cur += 3072;   // NB*64*16
  long oNL2 = cur;  cur += 6144;   // NB*64*32
  long oNL3 = cur;  cur += 6144;
  long oNL1 = cur;  cur += 6144;
  long oGIH = cur;  cur += 6144;   // 192*32
  long oGHH = cur;  cur += 6144;
  long baseEnd = cur;

  float* S0   = f + oS0;
  float* S1   = f + oS1;
  float* hxb  = f + oHX;
  float* aggb = f + oAG;
  float* Cp   = f + oCP;
  float* dinv = f + oDI;
  float* ebuf = f + oEB;
  int*   degi = (int*)(f + oEB);
  float* qstar= f + oQ;
  float* hl   = f + oHL;
  float* cls  = f + oCL;
  int*   bounds = (int*)(f + oBN);
  int*   es   = (int*)(f + oES);
  int*   ssrc = (int*)(f + oSR);
  int*   sdst = (int*)(f + oSD);
  int*   startA = (int*)(f + oST);
  int*   bsum = (int*)(f + oBS);
  unsigned int* w1h  = (unsigned int*)(f + oW1H);
  unsigned int* w2h  = (unsigned int*)(f + oW2H);
  unsigned int* nl2h = (unsigned int*)(f + oNL2);
  unsigned int* nl3h = (unsigned int*)(f + oNL3);
  unsigned int* nl1h = (unsigned int*)(f + oNL1);
  unsigned int* gih  = (unsigned int*)(f + oGIH);
  unsigned int* ghh  = (unsigned int*)(f + oGHH);

  // eap: slot-ordered f16-packed ea copy, NE*EAPW uints (112 MB)
  long wsF = (long)(ws_size / 4);
  int useEap = (baseEnd + (long)NE * EAPW <= wsF) ? 1 : 0;
  unsigned int* eap = (unsigned int*)(f + baseEnd);

  hipMemsetAsync(degi, 0, NN * sizeof(int), stream);
  hipMemsetAsync(qstar, 0, (NG * 2 * D + 2 * NG * D) * sizeof(float), stream);

  k_deg<<<(NE + 255) / 256, 256, 0, stream>>>(ei, degi);
  k_scan1<<<NB1, 256, 0, stream>>>(degi, startA, dinv, bsum);
  k_scan2<<<1, 256, 0, stream>>>(bsum);
  k_scan3<<<NB1, 256, 0, stream>>>(startA, bsum);
  if (useEap)
    k_slot2<1><<<(NE + 255) / 256, 256, 0, stream>>>(
        ei, ew, startA, degi, es, ssrc, sdst, Cp, ea, eap);
  else
    k_slot2<0><<<(NE + 255) / 256, 256, 0, stream>>>(
        ei, ew, startA, degi, es, ssrc, sdst, Cp, ea, eap);
  k_wprep<<<142, 256, 0, stream>>>(cw1, cw2, cl2w, cl3w, cl1w, gwih, gwhh,
                                   w1h, w2h, nl2h, nl3h, nl1h, gih, ghh);
  k_lin0q<<<dim3((NN + 255) / 256, 4), 256, 0, stream>>>(x, lin0_w, lin0_b, S0);
  k_bounds<<<1, 192, 0, stream>>>(batch, bounds);

  const int NBK = (NN + 63) / 64;
  k_stage<0><<<NBK, 256, 0, stream>>>(S0, cl1w, nullptr, hxb);

  for (int b = 0; b < NBLK; b++) {
    float* Sin  = (b & 1) ? S1 : S0;
    float* Sout = (b & 1) ? S0 : S1;
    hipMemsetAsync(aggb, 0, NND * sizeof(float), stream);
    if (useEap)
      k_econv4<1><<<(NE + 255) / 256, 256, 0, stream>>>(
          ea, eap, es, cw1 + b * 32 * EHD, w1h + b * 800, cb1 + b * 32,
          cw2 + b * D * 32, w2h + b * 1024, cb2 + b * D,
          Cp, ssrc, sdst, hxb, aggb);
    else
      k_econv4<0><<<(NE + 255) / 256, 256, 0, stream>>>(
          ea, eap, es, cw1 + b * 32 * EHD, w1h + b * 800, cb1 + b * 32,
          cw2 + b * D * 32, w2h + b * 1024, cb2 + b * D,
          Cp, ssrc, sdst, hxb, aggb);
    const unsigned int* w1nh = (b + 1 < NBLK) ? (nl1h + (b + 1) * 2048) : nullptr;
    k_nodeblk<<<NBK, 256, 0, stream>>>(aggb, dinv, Sin,
                                       nl2h + b * 2048, cl2b + b * D,
                                       nl3h + b * 2048, cl3b + b * D,
                                       gih, ghh, gbih, gbhh,
                                       Sout, w1nh, hxb);
  }

  float* Sfin = (NBLK & 1) ? S1 : S0;
  for (int it = 0; it < 3; it++) {
    k_s2s<<<NG, 256, 0, stream>>>(lwih, lwhh, lbih, lbhh, Sfin, bounds,
                                  qstar, hl, cls, ebuf);
  }

  k_final<<<NG, 64, 0, stream>>>(qstar, l1w, l1b, l2w, l2b, z, eref, aref,
                                 bounds, outp);
}